// Round 1
// baseline (326.634 us; speedup 1.0000x reference)
//
#include <hip/hip_runtime.h>
#include <hip/hip_bf16.h>

// Shapes: c1[4,256,128,128], c2[4,512,64,64], out[4,256,64,64],
//         w_refine[32,256], w_refine2[32,512]  -> result[4,256,128,128] (f32)

typedef float f32x4 __attribute__((ext_vector_type(4)));
typedef float uf4  __attribute__((ext_vector_type(4), aligned(4)));  // 4B-aligned vec load

#define SCL (63.0f / 127.0f)

// ---------------- K1: q = normalize_c( c1 @ w_refine^T ), layout [n*16384 pix][32]
__global__ __launch_bounds__(256) void k_q(const float* __restrict__ c1,
                                           const float* __restrict__ wr,
                                           float* __restrict__ q) {
    int p   = blockIdx.x * 256 + threadIdx.x;   // 0..65535 (n*16384 + y*128 + x)
    int n   = p >> 14;
    int rem = p & 16383;
    const float* src = c1 + (size_t)n * 256 * 16384 + rem;
    float acc[32];
#pragma unroll
    for (int k = 0; k < 32; ++k) acc[k] = 0.f;
#pragma unroll 4
    for (int c = 0; c < 256; ++c) {
        float v = src[(size_t)c * 16384];        // coalesced across lanes
#pragma unroll
        for (int k = 0; k < 32; ++k)
            acc[k] = fmaf(v, wr[k * 256 + c], acc[k]);  // wave-uniform -> s_load
    }
    float s = 0.f;
#pragma unroll
    for (int k = 0; k < 32; ++k) s = fmaf(acc[k], acc[k], s);
    float inv = 1.0f / fmaxf(sqrtf(s), 1e-12f);
    f32x4* dst = (f32x4*)(q + (size_t)p * 32);
#pragma unroll
    for (int j = 0; j < 8; ++j) {
        f32x4 t = { acc[4*j]*inv, acc[4*j+1]*inv, acc[4*j+2]*inv, acc[4*j+3]*inv };
        dst[j] = t;
    }
}

// ---------------- K2: kfs = c2 @ w_refine2^T at 64x64 (UNNORMALIZED), [n*4096 pix][32]
__global__ __launch_bounds__(256) void k_kfs(const float* __restrict__ c2,
                                             const float* __restrict__ wr2,
                                             float* __restrict__ kfs) {
    int p   = blockIdx.x * 256 + threadIdx.x;   // 0..16383
    int n   = p >> 12;
    int rem = p & 4095;
    const float* src = c2 + (size_t)n * 512 * 4096 + rem;
    float acc[32];
#pragma unroll
    for (int k = 0; k < 32; ++k) acc[k] = 0.f;
#pragma unroll 4
    for (int c = 0; c < 512; ++c) {
        float v = src[(size_t)c * 4096];
#pragma unroll
        for (int k = 0; k < 32; ++k)
            acc[k] = fmaf(v, wr2[k * 512 + c], acc[k]);
    }
    f32x4* dst = (f32x4*)(kfs + (size_t)p * 32);
#pragma unroll
    for (int j = 0; j < 8; ++j) {
        f32x4 t = { acc[4*j], acc[4*j+1], acc[4*j+2], acc[4*j+3] };
        dst[j] = t;
    }
}

// ---------------- K3: kft = normalize_c( bilinear_up(kfs, 64->128) ), [n*16384 pix][32]
__global__ __launch_bounds__(256) void k_upnorm(const float* __restrict__ kfs,
                                                float* __restrict__ kft) {
    int p   = blockIdx.x * 256 + threadIdx.x;   // 0..65535
    int n   = p >> 14;
    int rem = p & 16383;
    int y = rem >> 7, x = rem & 127;
    float syf = SCL * (float)y; int y0 = (int)syf; float fy = syf - (float)y0;
    int y1 = min(y0 + 1, 63);
    float sxf = SCL * (float)x; int x0 = (int)sxf; float fx = sxf - (float)x0;
    int x1 = min(x0 + 1, 63);
    size_t base = (size_t)n * 4096 * 32;
    const f32x4* p00 = (const f32x4*)(kfs + base + ((size_t)(y0 * 64 + x0)) * 32);
    const f32x4* p01 = (const f32x4*)(kfs + base + ((size_t)(y0 * 64 + x1)) * 32);
    const f32x4* p10 = (const f32x4*)(kfs + base + ((size_t)(y1 * 64 + x0)) * 32);
    const f32x4* p11 = (const f32x4*)(kfs + base + ((size_t)(y1 * 64 + x1)) * 32);
    float w00 = (1.f-fy)*(1.f-fx), w01 = (1.f-fy)*fx, w10 = fy*(1.f-fx), w11 = fy*fx;
    float v[32]; float s = 0.f;
#pragma unroll
    for (int j = 0; j < 8; ++j) {
        f32x4 a = p00[j], b = p01[j], c = p10[j], d = p11[j];
#pragma unroll
        for (int t = 0; t < 4; ++t) {
            float r = a[t]*w00 + b[t]*w01 + c[t]*w10 + d[t]*w11;
            v[4*j + t] = r;
            s = fmaf(r, r, s);
        }
    }
    float inv = 1.0f / fmaxf(sqrtf(s), 1e-12f);
    f32x4* dst = (f32x4*)(kft + (size_t)p * 32);
#pragma unroll
    for (int j = 0; j < 8; ++j) {
        f32x4 t = { v[4*j]*inv, v[4*j+1]*inv, v[4*j+2]*inv, v[4*j+3]*inv };
        dst[j] = t;
    }
}

// ---------------- K4: energies -> softmax -> combined 4x4 weights -> aggregate out planes
// block = 256 thr: tid&127 = x (one row y per block), tid>>7 = channel group (128 ch each)
__global__ __launch_bounds__(256) void k_att_agg(const float* __restrict__ q,
                                                 const float* __restrict__ kft,
                                                 const float* __restrict__ outp,
                                                 float* __restrict__ res) {
    __shared__ float wlds[128 * 17];
    int b = blockIdx.x;            // 0..511
    int n = b >> 7, y = b & 127;
    int tid = threadIdx.x;
    int x = tid & 127, cg = tid >> 7;

    int ybase = min((int)(SCL * (float)max(y - 2, 0)), 60);
    int xbase = min((int)(SCL * (float)max(x - 2, 0)), 60);

    if (tid < 128) {
        // load q vector (contiguous 128B)
        float qv[32];
        const f32x4* qp = (const f32x4*)(q + ((size_t)n * 16384 + y * 128 + x) * 32);
#pragma unroll
        for (int j = 0; j < 8; ++j) {
            f32x4 t = qp[j];
            qv[4*j] = t[0]; qv[4*j+1] = t[1]; qv[4*j+2] = t[2]; qv[4*j+3] = t[3];
        }
        // energies over 9 dilated neighbors (OOB -> 0, matches zero-padded unfold)
        float e[9];
#pragma unroll
        for (int k = 0; k < 9; ++k) {
            int ky = k / 3, kx = k % 3;
            int ny = y + 2 * ky - 2, nx = x + 2 * kx - 2;
            float acc = 0.f;
            if (ny >= 0 && ny < 128 && nx >= 0 && nx < 128) {
                const f32x4* kp = (const f32x4*)(kft + ((size_t)n * 16384 + ny * 128 + nx) * 32);
#pragma unroll
                for (int j = 0; j < 8; ++j) {
                    f32x4 t = kp[j];
                    acc = fmaf(t[0], qv[4*j],   acc);
                    acc = fmaf(t[1], qv[4*j+1], acc);
                    acc = fmaf(t[2], qv[4*j+2], acc);
                    acc = fmaf(t[3], qv[4*j+3], acc);
                }
            }
            e[k] = acc;
        }
        // softmax over 9 (OOB e=0 participates)
        float m = e[0];
#pragma unroll
        for (int k = 1; k < 9; ++k) m = fmaxf(m, e[k]);
        float ssum = 0.f;
#pragma unroll
        for (int k = 0; k < 9; ++k) { e[k] = __expf(e[k] - m); ssum += e[k]; }
        float rinv = 1.0f / ssum;

        // scatter att * bilinear weights into a 4x4 window at (ybase, xbase)
        float* wp = wlds + x * 17;
#pragma unroll
        for (int i = 0; i < 16; ++i) wp[i] = 0.f;
#pragma unroll
        for (int ky = 0; ky < 3; ++ky) {
            int ny = y + 2 * ky - 2;
            if (ny < 0 || ny > 127) continue;
            float syf = SCL * (float)ny; int iy0 = (int)syf; float fy = syf - (float)iy0;
            int iy1 = min(iy0 + 1, 63);
            int r0 = (iy0 - ybase) * 4, r1 = (iy1 - ybase) * 4;
#pragma unroll
            for (int kx = 0; kx < 3; ++kx) {
                int nx = x + 2 * kx - 2;
                if (nx < 0 || nx > 127) continue;
                float sxf = SCL * (float)nx; int ix0 = (int)sxf; float fx = sxf - (float)ix0;
                int ix1 = min(ix0 + 1, 63);
                float a = e[ky * 3 + kx] * rinv;
                wp[r0 + (ix0 - xbase)] += a * (1.f - fy) * (1.f - fx);
                wp[r0 + (ix1 - xbase)] += a * (1.f - fy) * fx;
                wp[r1 + (ix0 - xbase)] += a * fy * (1.f - fx);
                wp[r1 + (ix1 - xbase)] += a * fy * fx;
            }
        }
    }
    __syncthreads();

    // phase 2: every thread aggregates 128 channels with the 16 combined weights
    float w16[16];
    const float* wrd = wlds + x * 17;
#pragma unroll
    for (int i = 0; i < 16; ++i) w16[i] = wrd[i];

    const float* obase = outp + (size_t)n * 256 * 4096 + (size_t)(ybase * 64 + xbase);
    float* rbase = res + (size_t)n * 256 * 16384 + (size_t)(y * 128 + x);
#pragma unroll 4
    for (int cc = 0; cc < 128; ++cc) {
        int c = cg * 128 + cc;
        const float* pl = obase + (size_t)c * 4096;
        float acc = 0.f;
#pragma unroll
        for (int ty = 0; ty < 4; ++ty) {
            uf4 r = *(const uf4*)(pl + ty * 64);   // rows ybase..ybase+3, cols xbase..+3 (in-bounds by clamp)
            acc = fmaf(r[0], w16[ty*4],   acc);
            acc = fmaf(r[1], w16[ty*4+1], acc);
            acc = fmaf(r[2], w16[ty*4+2], acc);
            acc = fmaf(r[3], w16[ty*4+3], acc);
        }
        rbase[(size_t)c * 16384] = acc;
    }
}

extern "C" void kernel_launch(void* const* d_in, const int* in_sizes, int n_in,
                              void* d_out, int out_size, void* d_ws, size_t ws_size,
                              hipStream_t stream) {
    const float* c1   = (const float*)d_in[0];
    const float* c2   = (const float*)d_in[1];
    const float* outp = (const float*)d_in[2];
    const float* wr   = (const float*)d_in[3];
    const float* wr2  = (const float*)d_in[4];
    float* res = (float*)d_out;

    // workspace: q [65536*32] f32 (8.39MB) | kfs [16384*32] f32 (2.10MB) | kft [65536*32] f32 (8.39MB)
    float* q_ws   = (float*)d_ws;
    float* kfs_ws = (float*)((char*)d_ws + 8388608);
    float* kft_ws = (float*)((char*)d_ws + 8388608 + 2097152);

    hipLaunchKernelGGL(k_q,      dim3(256), dim3(256), 0, stream, c1, wr, q_ws);
    hipLaunchKernelGGL(k_kfs,    dim3(64),  dim3(256), 0, stream, c2, wr2, kfs_ws);
    hipLaunchKernelGGL(k_upnorm, dim3(256), dim3(256), 0, stream, kfs_ws, kft_ws);
    hipLaunchKernelGGL(k_att_agg,dim3(512), dim3(256), 0, stream, q_ws, kft_ws, outp, res);
}

// Round 2
// 137.175 us; speedup vs baseline: 2.3811x; 2.3811x over previous
//
#include <hip/hip_runtime.h>
#include <hip/hip_bf16.h>

// Shapes: c1[4,256,128,128], c2[4,512,64,64], out[4,256,64,64],
//         w_refine[32,256], w_refine2[32,512]  -> result[4,256,128,128] (f32)

typedef float f32x4 __attribute__((ext_vector_type(4)));
typedef float uf4  __attribute__((ext_vector_type(4), aligned(4)));  // 4B-aligned vec load

#define SCL (63.0f / 127.0f)

// ---------------- K1: q = normalize_c( c1 @ w_refine^T ), layout [n*16384 pix][32]
// 1024 blocks x 256 thr. Block = 64 pixels; wave g handles channels [g*64, g*64+64).
__global__ __launch_bounds__(256) void k_q(const float* __restrict__ c1,
                                           const float* __restrict__ wr,
                                           float* __restrict__ q) {
    __shared__ float red[4 * 64 * 33];   // [group][pixel][33] padded
    int b = blockIdx.x;                  // 256 blocks per n
    int n = b >> 8;
    int pblk = (b & 255) * 64;
    int t = threadIdx.x;
    int lane = t & 63;
    int gbase = __builtin_amdgcn_readfirstlane((t >> 6) << 6);  // wave-uniform ch base

    const float* src = c1 + ((size_t)n * 256 + gbase) * 16384 + pblk + lane;
    float acc[32];
#pragma unroll
    for (int k = 0; k < 32; ++k) acc[k] = 0.f;
#pragma unroll 8
    for (int c = 0; c < 64; ++c) {
        float v = src[(size_t)c * 16384];                 // coalesced 256B/wave
#pragma unroll
        for (int k = 0; k < 32; ++k)
            acc[k] = fmaf(v, wr[k * 256 + gbase + c], acc[k]);  // scalar s_load
    }
    float* wp = red + (t >> 6) * (64 * 33) + lane * 33;
#pragma unroll
    for (int k = 0; k < 32; ++k) wp[k] = acc[k];
    __syncthreads();

    if (t < 64) {
        float v[32]; float s = 0.f;
#pragma unroll
        for (int k = 0; k < 32; ++k) {
            float r = red[0*2112 + t*33 + k] + red[1*2112 + t*33 + k]
                    + red[2*2112 + t*33 + k] + red[3*2112 + t*33 + k];
            v[k] = r; s = fmaf(r, r, s);
        }
        float inv = 1.0f / fmaxf(sqrtf(s), 1e-12f);
        f32x4* dst = (f32x4*)(q + ((size_t)n * 16384 + pblk + t) * 32);
#pragma unroll
        for (int j = 0; j < 8; ++j) {
            f32x4 o = { v[4*j]*inv, v[4*j+1]*inv, v[4*j+2]*inv, v[4*j+3]*inv };
            dst[j] = o;
        }
    }
}

// ---------------- K2: kfs = c2 @ w_refine2^T at 64x64 (UNNORMALIZED), [n*4096 pix][32]
// 256 blocks x 512 thr. Block = 64 pixels; wave g handles channels [g*64, g*64+64).
__global__ __launch_bounds__(512) void k_kfs(const float* __restrict__ c2,
                                             const float* __restrict__ wr2,
                                             float* __restrict__ kfs) {
    __shared__ float red[8 * 64 * 33];   // 67.6 KB
    int b = blockIdx.x;                  // 64 blocks per n
    int n = b >> 6;
    int pblk = (b & 63) * 64;
    int t = threadIdx.x;
    int lane = t & 63;
    int gbase = __builtin_amdgcn_readfirstlane((t >> 6) << 6);

    const float* src = c2 + ((size_t)n * 512 + gbase) * 4096 + pblk + lane;
    float acc[32];
#pragma unroll
    for (int k = 0; k < 32; ++k) acc[k] = 0.f;
#pragma unroll 8
    for (int c = 0; c < 64; ++c) {
        float v = src[(size_t)c * 4096];
#pragma unroll
        for (int k = 0; k < 32; ++k)
            acc[k] = fmaf(v, wr2[k * 512 + gbase + c], acc[k]);
    }
    float* wp = red + (t >> 6) * (64 * 33) + lane * 33;
#pragma unroll
    for (int k = 0; k < 32; ++k) wp[k] = acc[k];
    __syncthreads();

    if (t < 128) {
        int pix = t >> 1, kh = (t & 1) * 16;
        float v[16];
#pragma unroll
        for (int k = 0; k < 16; ++k) {
            float r = 0.f;
#pragma unroll
            for (int g = 0; g < 8; ++g) r += red[g*2112 + pix*33 + kh + k];
            v[k] = r;
        }
        f32x4* dst = (f32x4*)(kfs + ((size_t)n * 4096 + pblk + pix) * 32 + kh);
#pragma unroll
        for (int j = 0; j < 4; ++j) {
            f32x4 o = { v[4*j], v[4*j+1], v[4*j+2], v[4*j+3] };
            dst[j] = o;
        }
    }
}

// ---------------- K3: kft = normalize_c( bilinear_up(kfs, 64->128) ), [n*16384 pix][32]
__global__ __launch_bounds__(256) void k_upnorm(const float* __restrict__ kfs,
                                                float* __restrict__ kft) {
    int p   = blockIdx.x * 256 + threadIdx.x;   // 0..65535
    int n   = p >> 14;
    int rem = p & 16383;
    int y = rem >> 7, x = rem & 127;
    float syf = SCL * (float)y; int y0 = (int)syf; float fy = syf - (float)y0;
    int y1 = min(y0 + 1, 63);
    float sxf = SCL * (float)x; int x0 = (int)sxf; float fx = sxf - (float)x0;
    int x1 = min(x0 + 1, 63);
    size_t base = (size_t)n * 4096 * 32;
    const f32x4* p00 = (const f32x4*)(kfs + base + ((size_t)(y0 * 64 + x0)) * 32);
    const f32x4* p01 = (const f32x4*)(kfs + base + ((size_t)(y0 * 64 + x1)) * 32);
    const f32x4* p10 = (const f32x4*)(kfs + base + ((size_t)(y1 * 64 + x0)) * 32);
    const f32x4* p11 = (const f32x4*)(kfs + base + ((size_t)(y1 * 64 + x1)) * 32);
    float w00 = (1.f-fy)*(1.f-fx), w01 = (1.f-fy)*fx, w10 = fy*(1.f-fx), w11 = fy*fx;
    float v[32]; float s = 0.f;
#pragma unroll
    for (int j = 0; j < 8; ++j) {
        f32x4 a = p00[j], b = p01[j], c = p10[j], d = p11[j];
#pragma unroll
        for (int tt = 0; tt < 4; ++tt) {
            float r = a[tt]*w00 + b[tt]*w01 + c[tt]*w10 + d[tt]*w11;
            v[4*j + tt] = r;
            s = fmaf(r, r, s);
        }
    }
    float inv = 1.0f / fmaxf(sqrtf(s), 1e-12f);
    f32x4* dst = (f32x4*)(kft + (size_t)p * 32);
#pragma unroll
    for (int j = 0; j < 8; ++j) {
        f32x4 t = { v[4*j]*inv, v[4*j+1]*inv, v[4*j+2]*inv, v[4*j+3]*inv };
        dst[j] = t;
    }
}

// ---------------- K4: energies -> softmax -> combined 4x4 weights -> aggregate out planes
// block = 256 thr: tid&127 = x (one row y per block), tid>>7 = channel group (128 ch each)
__global__ __launch_bounds__(256) void k_att_agg(const float* __restrict__ q,
                                                 const float* __restrict__ kft,
                                                 const float* __restrict__ outp,
                                                 float* __restrict__ res) {
    __shared__ float wlds[128 * 17];
    int b = blockIdx.x;            // 0..511
    int n = b >> 7, y = b & 127;
    int tid = threadIdx.x;
    int x = tid & 127, cg = tid >> 7;

    int ybase = min((int)(SCL * (float)max(y - 2, 0)), 60);
    int xbase = min((int)(SCL * (float)max(x - 2, 0)), 60);

    if (tid < 128) {
        float qv[32];
        const f32x4* qp = (const f32x4*)(q + ((size_t)n * 16384 + y * 128 + x) * 32);
#pragma unroll
        for (int j = 0; j < 8; ++j) {
            f32x4 t = qp[j];
            qv[4*j] = t[0]; qv[4*j+1] = t[1]; qv[4*j+2] = t[2]; qv[4*j+3] = t[3];
        }
        float e[9];
#pragma unroll
        for (int k = 0; k < 9; ++k) {
            int ky = k / 3, kx = k % 3;
            int ny = y + 2 * ky - 2, nx = x + 2 * kx - 2;
            float acc = 0.f;
            if (ny >= 0 && ny < 128 && nx >= 0 && nx < 128) {
                const f32x4* kp = (const f32x4*)(kft + ((size_t)n * 16384 + ny * 128 + nx) * 32);
#pragma unroll
                for (int j = 0; j < 8; ++j) {
                    f32x4 t = kp[j];
                    acc = fmaf(t[0], qv[4*j],   acc);
                    acc = fmaf(t[1], qv[4*j+1], acc);
                    acc = fmaf(t[2], qv[4*j+2], acc);
                    acc = fmaf(t[3], qv[4*j+3], acc);
                }
            }
            e[k] = acc;
        }
        float m = e[0];
#pragma unroll
        for (int k = 1; k < 9; ++k) m = fmaxf(m, e[k]);
        float ssum = 0.f;
#pragma unroll
        for (int k = 0; k < 9; ++k) { e[k] = __expf(e[k] - m); ssum += e[k]; }
        float rinv = 1.0f / ssum;

        float* wp = wlds + x * 17;
#pragma unroll
        for (int i = 0; i < 16; ++i) wp[i] = 0.f;
#pragma unroll
        for (int ky = 0; ky < 3; ++ky) {
            int ny = y + 2 * ky - 2;
            if (ny < 0 || ny > 127) continue;
            float syf = SCL * (float)ny; int iy0 = (int)syf; float fy = syf - (float)iy0;
            int iy1 = min(iy0 + 1, 63);
            int r0 = (iy0 - ybase) * 4, r1 = (iy1 - ybase) * 4;
#pragma unroll
            for (int kx = 0; kx < 3; ++kx) {
                int nx = x + 2 * kx - 2;
                if (nx < 0 || nx > 127) continue;
                float sxf = SCL * (float)nx; int ix0 = (int)sxf; float fx = sxf - (float)ix0;
                int ix1 = min(ix0 + 1, 63);
                float a = e[ky * 3 + kx] * rinv;
                wp[r0 + (ix0 - xbase)] += a * (1.f - fy) * (1.f - fx);
                wp[r0 + (ix1 - xbase)] += a * (1.f - fy) * fx;
                wp[r1 + (ix0 - xbase)] += a * fy * (1.f - fx);
                wp[r1 + (ix1 - xbase)] += a * fy * fx;
            }
        }
    }
    __syncthreads();

    float w16[16];
    const float* wrd = wlds + x * 17;
#pragma unroll
    for (int i = 0; i < 16; ++i) w16[i] = wrd[i];

    const float* obase = outp + (size_t)n * 256 * 4096 + (size_t)(ybase * 64 + xbase);
    float* rbase = res + (size_t)n * 256 * 16384 + (size_t)(y * 128 + x);
#pragma unroll 4
    for (int cc = 0; cc < 128; ++cc) {
        int c = cg * 128 + cc;
        const float* pl = obase + (size_t)c * 4096;
        float acc = 0.f;
#pragma unroll
        for (int ty = 0; ty < 4; ++ty) {
            uf4 r = *(const uf4*)(pl + ty * 64);
            acc = fmaf(r[0], w16[ty*4],   acc);
            acc = fmaf(r[1], w16[ty*4+1], acc);
            acc = fmaf(r[2], w16[ty*4+2], acc);
            acc = fmaf(r[3], w16[ty*4+3], acc);
        }
        rbase[(size_t)c * 16384] = acc;
    }
}

extern "C" void kernel_launch(void* const* d_in, const int* in_sizes, int n_in,
                              void* d_out, int out_size, void* d_ws, size_t ws_size,
                              hipStream_t stream) {
    const float* c1   = (const float*)d_in[0];
    const float* c2   = (const float*)d_in[1];
    const float* outp = (const float*)d_in[2];
    const float* wr   = (const float*)d_in[3];
    const float* wr2  = (const float*)d_in[4];
    float* res = (float*)d_out;

    // workspace: q [65536*32] f32 (8.39MB) | kfs [16384*32] f32 (2.10MB) | kft [65536*32] f32 (8.39MB)
    float* q_ws   = (float*)d_ws;
    float* kfs_ws = (float*)((char*)d_ws + 8388608);
    float* kft_ws = (float*)((char*)d_ws + 8388608 + 2097152);

    hipLaunchKernelGGL(k_q,      dim3(1024), dim3(256), 0, stream, c1, wr, q_ws);
    hipLaunchKernelGGL(k_kfs,    dim3(256),  dim3(512), 0, stream, c2, wr2, kfs_ws);
    hipLaunchKernelGGL(k_upnorm, dim3(256),  dim3(256), 0, stream, kfs_ws, kft_ws);
    hipLaunchKernelGGL(k_att_agg,dim3(512),  dim3(256), 0, stream, q_ws, kft_ws, outp, res);
}

// Round 3
// 130.874 us; speedup vs baseline: 2.4958x; 1.0481x over previous
//
#include <hip/hip_runtime.h>
#include <hip/hip_bf16.h>

// Shapes: c1[4,256,128,128], c2[4,512,64,64], out[4,256,64,64],
//         w_refine[32,256], w_refine2[32,512]  -> result[4,256,128,128] (f32)

typedef float f32x4 __attribute__((ext_vector_type(4)));

#define SCL (63.0f / 127.0f)

// ---------------- K1: q = normalize_c( c1 @ w_refine^T ), layout [n*16384 pix][32]
// 1024 blocks x 256 thr. Block = 64 pixels; wave g handles channels [g*64, g*64+64).
__global__ __launch_bounds__(256) void k_q(const float* __restrict__ c1,
                                           const float* __restrict__ wr,
                                           float* __restrict__ q) {
    __shared__ float red[4 * 64 * 33];   // [group][pixel][33] padded
    int b = blockIdx.x;                  // 256 blocks per n
    int n = b >> 8;
    int pblk = (b & 255) * 64;
    int t = threadIdx.x;
    int lane = t & 63;
    int gbase = __builtin_amdgcn_readfirstlane((t >> 6) << 6);  // wave-uniform ch base

    const float* src = c1 + ((size_t)n * 256 + gbase) * 16384 + pblk + lane;
    float acc[32];
#pragma unroll
    for (int k = 0; k < 32; ++k) acc[k] = 0.f;
#pragma unroll 8
    for (int c = 0; c < 64; ++c) {
        float v = src[(size_t)c * 16384];                 // coalesced 256B/wave
#pragma unroll
        for (int k = 0; k < 32; ++k)
            acc[k] = fmaf(v, wr[k * 256 + gbase + c], acc[k]);  // scalar s_load
    }
    float* wp = red + (t >> 6) * (64 * 33) + lane * 33;
#pragma unroll
    for (int k = 0; k < 32; ++k) wp[k] = acc[k];
    __syncthreads();

    if (t < 64) {
        float v[32]; float s = 0.f;
#pragma unroll
        for (int k = 0; k < 32; ++k) {
            float r = red[0*2112 + t*33 + k] + red[1*2112 + t*33 + k]
                    + red[2*2112 + t*33 + k] + red[3*2112 + t*33 + k];
            v[k] = r; s = fmaf(r, r, s);
        }
        float inv = 1.0f / fmaxf(sqrtf(s), 1e-12f);
        f32x4* dst = (f32x4*)(q + ((size_t)n * 16384 + pblk + t) * 32);
#pragma unroll
        for (int j = 0; j < 8; ++j) {
            f32x4 o = { v[4*j]*inv, v[4*j+1]*inv, v[4*j+2]*inv, v[4*j+3]*inv };
            dst[j] = o;
        }
    }
}

// ---------------- K2: kfs = c2 @ w_refine2^T at 64x64 (UNNORMALIZED), [n*4096 pix][32]
__global__ __launch_bounds__(512) void k_kfs(const float* __restrict__ c2,
                                             const float* __restrict__ wr2,
                                             float* __restrict__ kfs) {
    __shared__ float red[8 * 64 * 33];   // 67.6 KB
    int b = blockIdx.x;                  // 64 blocks per n
    int n = b >> 6;
    int pblk = (b & 63) * 64;
    int t = threadIdx.x;
    int lane = t & 63;
    int gbase = __builtin_amdgcn_readfirstlane((t >> 6) << 6);

    const float* src = c2 + ((size_t)n * 512 + gbase) * 4096 + pblk + lane;
    float acc[32];
#pragma unroll
    for (int k = 0; k < 32; ++k) acc[k] = 0.f;
#pragma unroll 8
    for (int c = 0; c < 64; ++c) {
        float v = src[(size_t)c * 4096];
#pragma unroll
        for (int k = 0; k < 32; ++k)
            acc[k] = fmaf(v, wr2[k * 512 + gbase + c], acc[k]);
    }
    float* wp = red + (t >> 6) * (64 * 33) + lane * 33;
#pragma unroll
    for (int k = 0; k < 32; ++k) wp[k] = acc[k];
    __syncthreads();

    if (t < 128) {
        int pix = t >> 1, kh = (t & 1) * 16;
        float v[16];
#pragma unroll
        for (int k = 0; k < 16; ++k) {
            float r = 0.f;
#pragma unroll
            for (int g = 0; g < 8; ++g) r += red[g*2112 + pix*33 + kh + k];
            v[k] = r;
        }
        f32x4* dst = (f32x4*)(kfs + ((size_t)n * 4096 + pblk + pix) * 32 + kh);
#pragma unroll
        for (int j = 0; j < 4; ++j) {
            f32x4 o = { v[4*j], v[4*j+1], v[4*j+2], v[4*j+3] };
            dst[j] = o;
        }
    }
}

// ---------------- K3: kft = normalize_c( bilinear_up(kfs, 64->128) ), [n*16384 pix][32]
__global__ __launch_bounds__(256) void k_upnorm(const float* __restrict__ kfs,
                                                float* __restrict__ kft) {
    int p   = blockIdx.x * 256 + threadIdx.x;   // 0..65535
    int n   = p >> 14;
    int rem = p & 16383;
    int y = rem >> 7, x = rem & 127;
    float syf = SCL * (float)y; int y0 = (int)syf; float fy = syf - (float)y0;
    int y1 = min(y0 + 1, 63);
    float sxf = SCL * (float)x; int x0 = (int)sxf; float fx = sxf - (float)x0;
    int x1 = min(x0 + 1, 63);
    size_t base = (size_t)n * 4096 * 32;
    const f32x4* p00 = (const f32x4*)(kfs + base + ((size_t)(y0 * 64 + x0)) * 32);
    const f32x4* p01 = (const f32x4*)(kfs + base + ((size_t)(y0 * 64 + x1)) * 32);
    const f32x4* p10 = (const f32x4*)(kfs + base + ((size_t)(y1 * 64 + x0)) * 32);
    const f32x4* p11 = (const f32x4*)(kfs + base + ((size_t)(y1 * 64 + x1)) * 32);
    float w00 = (1.f-fy)*(1.f-fx), w01 = (1.f-fy)*fx, w10 = fy*(1.f-fx), w11 = fy*fx;
    float v[32]; float s = 0.f;
#pragma unroll
    for (int j = 0; j < 8; ++j) {
        f32x4 a = p00[j], b = p01[j], c = p10[j], d = p11[j];
#pragma unroll
        for (int tt = 0; tt < 4; ++tt) {
            float r = a[tt]*w00 + b[tt]*w01 + c[tt]*w10 + d[tt]*w11;
            v[4*j + tt] = r;
            s = fmaf(r, r, s);
        }
    }
    float inv = 1.0f / fmaxf(sqrtf(s), 1e-12f);
    f32x4* dst = (f32x4*)(kft + (size_t)p * 32);
#pragma unroll
    for (int j = 0; j < 8; ++j) {
        f32x4 t = { v[4*j]*inv, v[4*j+1]*inv, v[4*j+2]*inv, v[4*j+3]*inv };
        dst[j] = t;
    }
}

// ---------------- K4a: energies -> softmax -> 16 combined bilinear weights per pixel
// wbuf layout TRANSPOSED: wbuf[i*65536 + p], i in [0,16)
__global__ __launch_bounds__(256) void k_att_w(const float* __restrict__ q,
                                               const float* __restrict__ kft,
                                               float* __restrict__ wbuf) {
    __shared__ float wsc[256 * 17];      // per-thread 16-slot scatter scratch (runtime idx -> LDS)
    int t = threadIdx.x;
    int p = blockIdx.x * 256 + t;        // 0..65535
    int n = p >> 14, rem = p & 16383;
    int y = rem >> 7, x = rem & 127;

    int ybase = min((int)(SCL * (float)max(y - 2, 0)), 60);
    int xbase = min((int)(SCL * (float)max(x - 2, 0)), 60);

    float qv[32];
    const f32x4* qp = (const f32x4*)(q + (size_t)p * 32);
#pragma unroll
    for (int j = 0; j < 8; ++j) {
        f32x4 v = qp[j];
        qv[4*j] = v[0]; qv[4*j+1] = v[1]; qv[4*j+2] = v[2]; qv[4*j+3] = v[3];
    }
    float e[9];
#pragma unroll
    for (int k = 0; k < 9; ++k) {
        int ky = k / 3, kx = k % 3;
        int ny = y + 2 * ky - 2, nx = x + 2 * kx - 2;
        float acc = 0.f;
        if (ny >= 0 && ny < 128 && nx >= 0 && nx < 128) {
            const f32x4* kp = (const f32x4*)(kft + ((size_t)n * 16384 + ny * 128 + nx) * 32);
#pragma unroll
            for (int j = 0; j < 8; ++j) {
                f32x4 v = kp[j];
                acc = fmaf(v[0], qv[4*j],   acc);
                acc = fmaf(v[1], qv[4*j+1], acc);
                acc = fmaf(v[2], qv[4*j+2], acc);
                acc = fmaf(v[3], qv[4*j+3], acc);
            }
        }
        e[k] = acc;
    }
    float m = e[0];
#pragma unroll
    for (int k = 1; k < 9; ++k) m = fmaxf(m, e[k]);
    float ssum = 0.f;
#pragma unroll
    for (int k = 0; k < 9; ++k) { e[k] = __expf(e[k] - m); ssum += e[k]; }
    float rinv = 1.0f / ssum;

    float* wp = wsc + t * 17;
#pragma unroll
    for (int i = 0; i < 16; ++i) wp[i] = 0.f;
#pragma unroll
    for (int ky = 0; ky < 3; ++ky) {
        int ny = y + 2 * ky - 2;
        if (ny < 0 || ny > 127) continue;
        float syf = SCL * (float)ny; int iy0 = (int)syf; float fy = syf - (float)iy0;
        int iy1 = min(iy0 + 1, 63);
        int r0 = (iy0 - ybase) * 4, r1 = (iy1 - ybase) * 4;
#pragma unroll
        for (int kx = 0; kx < 3; ++kx) {
            int nx = x + 2 * kx - 2;
            if (nx < 0 || nx > 127) continue;
            float sxf = SCL * (float)nx; int ix0 = (int)sxf; float fx = sxf - (float)ix0;
            int ix1 = min(ix0 + 1, 63);
            float a = e[ky * 3 + kx] * rinv;
            wp[r0 + (ix0 - xbase)] += a * (1.f - fy) * (1.f - fx);
            wp[r0 + (ix1 - xbase)] += a * (1.f - fy) * fx;
            wp[r1 + (ix0 - xbase)] += a * fy * (1.f - fx);
            wp[r1 + (ix1 - xbase)] += a * fy * fx;
        }
    }
    // coalesced transposed store
#pragma unroll
    for (int i = 0; i < 16; ++i) wbuf[i * 65536 + p] = wp[i];
}

// ---------------- K4b: aggregate out planes with combined weights (LDS-staged, dense loads)
// grid 2048 = n(4) x y(128) x cg(4); 256 thr: x = t&127, half = t>>7 (4 channels each)
__global__ __launch_bounds__(256) void k_agg(const float* __restrict__ wbuf,
                                             const float* __restrict__ outp,
                                             float* __restrict__ res) {
    __shared__ float wlds[128 * 17];
    __shared__ float tile[8 * 260];
    int b = blockIdx.x;
    int cg = b & 3, y = (b >> 2) & 127, n = b >> 9;
    int t = threadIdx.x;
    int x = t & 127, half = t >> 7;

    int ybase = min((int)(SCL * (float)max(y - 2, 0)), 60);
    int pix = n * 16384 + y * 128;

    // stage per-pixel weights: 16 x 128 floats, coalesced
#pragma unroll
    for (int k = 0; k < 8; ++k) {
        int u = t + 256 * k;
        int i = u >> 7, xx = u & 127;
        wlds[xx * 17 + i] = wbuf[i * 65536 + pix + xx];
    }
    __syncthreads();
    float w16[16];
#pragma unroll
    for (int i = 0; i < 16; ++i) w16[i] = wlds[x * 17 + i];
    int xb = min((int)(SCL * (float)max(x - 2, 0)), 60);

    const float* ob = outp + ((size_t)n * 256 + cg * 64) * 4096 + ybase * 64;
    float* rb = res + ((size_t)n * 256 + cg * 64) * 16384 + y * 128 + x;

#pragma unroll 1
    for (int batch = 0; batch < 8; ++batch) {
        __syncthreads();
        const float* src = ob + (size_t)batch * 8 * 4096;
#pragma unroll
        for (int k = 0; k < 2; ++k) {
            int u = t + 256 * k;               // 0..511 over 8ch x 64 float4
            int cl = u >> 6, seg = u & 63;     // (seg>>4)*64 + (seg&15)*4 == seg*4
            f32x4 v = *(const f32x4*)(src + (size_t)cl * 4096 + seg * 4);
            *(f32x4*)&tile[cl * 260 + seg * 4] = v;
        }
        __syncthreads();
#pragma unroll
        for (int cl = 0; cl < 4; ++cl) {
            int c = half * 4 + cl;
            const float* tp = tile + c * 260 + xb;
            float acc = 0.f;
#pragma unroll
            for (int r = 0; r < 4; ++r) {
                acc = fmaf(tp[r*64 + 0], w16[r*4 + 0], acc);
                acc = fmaf(tp[r*64 + 1], w16[r*4 + 1], acc);
                acc = fmaf(tp[r*64 + 2], w16[r*4 + 2], acc);
                acc = fmaf(tp[r*64 + 3], w16[r*4 + 3], acc);
            }
            rb[(size_t)(batch * 8 + c) * 16384] = acc;
        }
    }
}

extern "C" void kernel_launch(void* const* d_in, const int* in_sizes, int n_in,
                              void* d_out, int out_size, void* d_ws, size_t ws_size,
                              hipStream_t stream) {
    const float* c1   = (const float*)d_in[0];
    const float* c2   = (const float*)d_in[1];
    const float* outp = (const float*)d_in[2];
    const float* wr   = (const float*)d_in[3];
    const float* wr2  = (const float*)d_in[4];
    float* res = (float*)d_out;

    // ws: q 8.39MB | kfs 2.10MB | kft 8.39MB | wbuf 4.19MB  (total ~23.1MB)
    float* q_ws   = (float*)d_ws;
    float* kfs_ws = (float*)((char*)d_ws + 8388608);
    float* kft_ws = (float*)((char*)d_ws + 8388608 + 2097152);
    float* w_ws   = (float*)((char*)d_ws + 8388608 + 2097152 + 8388608);

    hipLaunchKernelGGL(k_q,      dim3(1024), dim3(256), 0, stream, c1, wr, q_ws);
    hipLaunchKernelGGL(k_kfs,    dim3(256),  dim3(512), 0, stream, c2, wr2, kfs_ws);
    hipLaunchKernelGGL(k_upnorm, dim3(256),  dim3(256), 0, stream, kfs_ws, kft_ws);
    hipLaunchKernelGGL(k_att_w,  dim3(256),  dim3(256), 0, stream, q_ws, kft_ws, w_ws);
    hipLaunchKernelGGL(k_agg,    dim3(2048), dim3(256), 0, stream, w_ws, outp, res);
}

// Round 4
// 87.161 us; speedup vs baseline: 3.7475x; 1.5015x over previous
//
#include <hip/hip_runtime.h>
#include <hip/hip_bf16.h>

// Shapes: c1[4,256,128,128], c2[4,512,64,64], out[4,256,64,64],
//         w_refine[32,256], w_refine2[32,512]  -> result[4,256,128,128] (f32)

typedef float f32x4 __attribute__((ext_vector_type(4)));
typedef float f32x2 __attribute__((ext_vector_type(2)));

#define SCL (63.0f / 127.0f)

// ---------------- K1: qraw = c1 @ w_refine^T (UNNORMALIZED; normalize fused into k_att_w)
// 512 blocks x 512 thr = 8 waves: wave = (cg in 4 x og in 2). 2 pixels/lane.
// Per chunk of 4 channels: 64 weight scalars (fits SGPR file), 128 FMA, 4 dwordx2 loads.
__global__ __launch_bounds__(512) void k_q(const float* __restrict__ c1,
                                           const float* __restrict__ wr,
                                           float* __restrict__ q) {
    __shared__ float red[4 * 32 * 130];    // [cg][k(32)][130] transposed, 66.6 KB
    int b = blockIdx.x;                    // 128 blocks per n
    int n = b >> 7;
    int pblk = (b & 127) * 128;
    int t = threadIdx.x;
    int lane = t & 63;
    int w = t >> 6;
    int cg = __builtin_amdgcn_readfirstlane(w & 3);    // channel group: 64 ch
    int og = __builtin_amdgcn_readfirstlane(w >> 2);   // output group: 16 out

    const float* src = c1 + ((size_t)n * 256 + cg * 64) * 16384 + pblk + lane * 2;
    const float* wp  = wr + (og * 16) * 256 + cg * 64;

    float acc0[16], acc1[16];
#pragma unroll
    for (int o = 0; o < 16; ++o) { acc0[o] = 0.f; acc1[o] = 0.f; }
#pragma unroll 4
    for (int c = 0; c < 64; ++c) {
        f32x2 v = *(const f32x2*)(src + (size_t)c * 16384);   // coalesced 512B/wave
#pragma unroll
        for (int o = 0; o < 16; ++o) {
            float wv = wp[o * 256 + c];                        // wave-uniform s_load
            acc0[o] = fmaf(v[0], wv, acc0[o]);
            acc1[o] = fmaf(v[1], wv, acc1[o]);
        }
    }
#pragma unroll
    for (int o = 0; o < 16; ++o) {
        f32x2 pr = { acc0[o], acc1[o] };
        *(f32x2*)&red[(cg * 32 + og * 16 + o) * 130 + lane * 2] = pr;  // 2-way bank alias = free
    }
    __syncthreads();

    if (t < 256) {
        int px = t & 127, half = t >> 7;
        float v[16];
#pragma unroll
        for (int o = 0; o < 16; ++o) {
            v[o] = red[(0 * 32 + half * 16 + o) * 130 + px]
                 + red[(1 * 32 + half * 16 + o) * 130 + px]
                 + red[(2 * 32 + half * 16 + o) * 130 + px]
                 + red[(3 * 32 + half * 16 + o) * 130 + px];
        }
        float* dst = q + ((size_t)n * 16384 + pblk + px) * 32 + half * 16;
#pragma unroll
        for (int j = 0; j < 4; ++j) {
            f32x4 o4 = { v[4*j], v[4*j+1], v[4*j+2], v[4*j+3] };
            *(f32x4*)(dst + 4 * j) = o4;
        }
    }
}

// ---------------- K2: kfs = c2 @ w_refine2^T at 64x64 (UNNORMALIZED), [n*4096 pix][32]
// 256 blocks x 1024 thr = 16 waves: wave = (cg in 8 x og in 2). 1 pixel/lane.
__global__ __launch_bounds__(1024) void k_kfs(const float* __restrict__ c2,
                                              const float* __restrict__ wr2,
                                              float* __restrict__ kfs) {
    __shared__ float red[8 * 32 * 66];     // [cg][k(32)][66] transposed, 67.6 KB
    int b = blockIdx.x;                    // 64 blocks per n
    int n = b >> 6;
    int pblk = (b & 63) * 64;
    int t = threadIdx.x;
    int lane = t & 63;
    int w = t >> 6;
    int cg = __builtin_amdgcn_readfirstlane(w & 7);    // 64 ch
    int og = __builtin_amdgcn_readfirstlane(w >> 3);   // 16 out

    const float* src = c2 + ((size_t)n * 512 + cg * 64) * 4096 + pblk + lane;
    const float* wp  = wr2 + (og * 16) * 512 + cg * 64;

    float acc[16];
#pragma unroll
    for (int o = 0; o < 16; ++o) acc[o] = 0.f;
#pragma unroll 4
    for (int c = 0; c < 64; ++c) {
        float v = src[(size_t)c * 4096];                      // coalesced 256B/wave
#pragma unroll
        for (int o = 0; o < 16; ++o)
            acc[o] = fmaf(v, wp[o * 512 + c], acc[o]);
    }
#pragma unroll
    for (int o = 0; o < 16; ++o)
        red[(cg * 32 + og * 16 + o) * 66 + lane] = acc[o];    // stride-1 lanes: conflict-free
    __syncthreads();

    if (t < 512) {
        int px = t & 63, seg = t >> 6;     // seg in [0,8): outputs seg*4..+4
        float v[4];
#pragma unroll
        for (int j = 0; j < 4; ++j) {
            float r = 0.f;
#pragma unroll
            for (int g = 0; g < 8; ++g) r += red[(g * 32 + seg * 4 + j) * 66 + px];
            v[j] = r;
        }
        f32x4 o4 = { v[0], v[1], v[2], v[3] };
        *(f32x4*)(kfs + ((size_t)n * 4096 + pblk + px) * 32 + seg * 4) = o4;
    }
}

// ---------------- K3: kft = normalize_c( bilinear_up(kfs, 64->128) ), [n*16384 pix][32]
__global__ __launch_bounds__(256) void k_upnorm(const float* __restrict__ kfs,
                                                float* __restrict__ kft) {
    int p   = blockIdx.x * 256 + threadIdx.x;   // 0..65535
    int n   = p >> 14;
    int rem = p & 16383;
    int y = rem >> 7, x = rem & 127;
    float syf = SCL * (float)y; int y0 = (int)syf; float fy = syf - (float)y0;
    int y1 = min(y0 + 1, 63);
    float sxf = SCL * (float)x; int x0 = (int)sxf; float fx = sxf - (float)x0;
    int x1 = min(x0 + 1, 63);
    size_t base = (size_t)n * 4096 * 32;
    const f32x4* p00 = (const f32x4*)(kfs + base + ((size_t)(y0 * 64 + x0)) * 32);
    const f32x4* p01 = (const f32x4*)(kfs + base + ((size_t)(y0 * 64 + x1)) * 32);
    const f32x4* p10 = (const f32x4*)(kfs + base + ((size_t)(y1 * 64 + x0)) * 32);
    const f32x4* p11 = (const f32x4*)(kfs + base + ((size_t)(y1 * 64 + x1)) * 32);
    float w00 = (1.f-fy)*(1.f-fx), w01 = (1.f-fy)*fx, w10 = fy*(1.f-fx), w11 = fy*fx;
    float v[32]; float s = 0.f;
#pragma unroll
    for (int j = 0; j < 8; ++j) {
        f32x4 a = p00[j], b = p01[j], c = p10[j], d = p11[j];
#pragma unroll
        for (int tt = 0; tt < 4; ++tt) {
            float r = a[tt]*w00 + b[tt]*w01 + c[tt]*w10 + d[tt]*w11;
            v[4*j + tt] = r;
            s = fmaf(r, r, s);
        }
    }
    float inv = 1.0f / fmaxf(sqrtf(s), 1e-12f);
    f32x4* dst = (f32x4*)(kft + (size_t)p * 32);
#pragma unroll
    for (int j = 0; j < 8; ++j) {
        f32x4 t = { v[4*j]*inv, v[4*j+1]*inv, v[4*j+2]*inv, v[4*j+3]*inv };
        dst[j] = t;
    }
}

// ---------------- K4a: normalize(q) -> energies -> softmax -> 16 combined weights
// wbuf layout TRANSPOSED: wbuf[i*65536 + p], i in [0,16)
__global__ __launch_bounds__(256) void k_att_w(const float* __restrict__ q,
                                               const float* __restrict__ kft,
                                               float* __restrict__ wbuf) {
    __shared__ float wsc[256 * 17];      // per-thread 16-slot scatter scratch
    int t = threadIdx.x;
    int p = blockIdx.x * 256 + t;        // 0..65535
    int n = p >> 14, rem = p & 16383;
    int y = rem >> 7, x = rem & 127;

    int ybase = min((int)(SCL * (float)max(y - 2, 0)), 60);
    int xbase = min((int)(SCL * (float)max(x - 2, 0)), 60);

    float qv[32];
    const f32x4* qp = (const f32x4*)(q + (size_t)p * 32);
    float qs = 0.f;
#pragma unroll
    for (int j = 0; j < 8; ++j) {
        f32x4 v = qp[j];
        qv[4*j] = v[0]; qv[4*j+1] = v[1]; qv[4*j+2] = v[2]; qv[4*j+3] = v[3];
        qs = fmaf(v[0], v[0], qs); qs = fmaf(v[1], v[1], qs);
        qs = fmaf(v[2], v[2], qs); qs = fmaf(v[3], v[3], qs);
    }
    float qinv = 1.0f / fmaxf(sqrtf(qs), 1e-12f);   // fused q-normalization
#pragma unroll
    for (int j = 0; j < 32; ++j) qv[j] *= qinv;

    float e[9];
#pragma unroll
    for (int k = 0; k < 9; ++k) {
        int ky = k / 3, kx = k % 3;
        int ny = y + 2 * ky - 2, nx = x + 2 * kx - 2;
        float acc = 0.f;
        if (ny >= 0 && ny < 128 && nx >= 0 && nx < 128) {
            const f32x4* kp = (const f32x4*)(kft + ((size_t)n * 16384 + ny * 128 + nx) * 32);
#pragma unroll
            for (int j = 0; j < 8; ++j) {
                f32x4 v = kp[j];
                acc = fmaf(v[0], qv[4*j],   acc);
                acc = fmaf(v[1], qv[4*j+1], acc);
                acc = fmaf(v[2], qv[4*j+2], acc);
                acc = fmaf(v[3], qv[4*j+3], acc);
            }
        }
        e[k] = acc;
    }
    float m = e[0];
#pragma unroll
    for (int k = 1; k < 9; ++k) m = fmaxf(m, e[k]);
    float ssum = 0.f;
#pragma unroll
    for (int k = 0; k < 9; ++k) { e[k] = __expf(e[k] - m); ssum += e[k]; }
    float rinv = 1.0f / ssum;

    float* wp = wsc + t * 17;
#pragma unroll
    for (int i = 0; i < 16; ++i) wp[i] = 0.f;
#pragma unroll
    for (int ky = 0; ky < 3; ++ky) {
        int ny = y + 2 * ky - 2;
        if (ny < 0 || ny > 127) continue;
        float syf = SCL * (float)ny; int iy0 = (int)syf; float fy = syf - (float)iy0;
        int iy1 = min(iy0 + 1, 63);
        int r0 = (iy0 - ybase) * 4, r1 = (iy1 - ybase) * 4;
#pragma unroll
        for (int kx = 0; kx < 3; ++kx) {
            int nx = x + 2 * kx - 2;
            if (nx < 0 || nx > 127) continue;
            float sxf = SCL * (float)nx; int ix0 = (int)sxf; float fx = sxf - (float)ix0;
            int ix1 = min(ix0 + 1, 63);
            float a = e[ky * 3 + kx] * rinv;
            wp[r0 + (ix0 - xbase)] += a * (1.f - fy) * (1.f - fx);
            wp[r0 + (ix1 - xbase)] += a * (1.f - fy) * fx;
            wp[r1 + (ix0 - xbase)] += a * fy * (1.f - fx);
            wp[r1 + (ix1 - xbase)] += a * fy * fx;
        }
    }
#pragma unroll
    for (int i = 0; i < 16; ++i) wbuf[i * 65536 + p] = wp[i];
}

// ---------------- K4b: aggregate out planes with combined weights (LDS-staged, dense loads)
// grid 2048 = n(4) x y(128) x cg(4); 256 thr: x = t&127, half = t>>7 (4 channels each)
__global__ __launch_bounds__(256) void k_agg(const float* __restrict__ wbuf,
                                             const float* __restrict__ outp,
                                             float* __restrict__ res) {
    __shared__ float wlds[128 * 17];
    __shared__ float tile[8 * 260];
    int b = blockIdx.x;
    int cg = b & 3, y = (b >> 2) & 127, n = b >> 9;
    int t = threadIdx.x;
    int x = t & 127, half = t >> 7;

    int ybase = min((int)(SCL * (float)max(y - 2, 0)), 60);
    int pix = n * 16384 + y * 128;

#pragma unroll
    for (int k = 0; k < 8; ++k) {
        int u = t + 256 * k;
        int i = u >> 7, xx = u & 127;
        wlds[xx * 17 + i] = wbuf[i * 65536 + pix + xx];
    }
    __syncthreads();
    float w16[16];
#pragma unroll
    for (int i = 0; i < 16; ++i) w16[i] = wlds[x * 17 + i];
    int xb = min((int)(SCL * (float)max(x - 2, 0)), 60);

    const float* ob = outp + ((size_t)n * 256 + cg * 64) * 4096 + ybase * 64;
    float* rb = res + ((size_t)n * 256 + cg * 64) * 16384 + y * 128 + x;

#pragma unroll 1
    for (int batch = 0; batch < 8; ++batch) {
        __syncthreads();
        const float* src = ob + (size_t)batch * 8 * 4096;
#pragma unroll
        for (int k = 0; k < 2; ++k) {
            int u = t + 256 * k;
            int cl = u >> 6, seg = u & 63;
            f32x4 v = *(const f32x4*)(src + (size_t)cl * 4096 + seg * 4);
            *(f32x4*)&tile[cl * 260 + seg * 4] = v;
        }
        __syncthreads();
#pragma unroll
        for (int cl = 0; cl < 4; ++cl) {
            int c = half * 4 + cl;
            const float* tp = tile + c * 260 + xb;
            float acc = 0.f;
#pragma unroll
            for (int r = 0; r < 4; ++r) {
                acc = fmaf(tp[r*64 + 0], w16[r*4 + 0], acc);
                acc = fmaf(tp[r*64 + 1], w16[r*4 + 1], acc);
                acc = fmaf(tp[r*64 + 2], w16[r*4 + 2], acc);
                acc = fmaf(tp[r*64 + 3], w16[r*4 + 3], acc);
            }
            rb[(size_t)(batch * 8 + c) * 16384] = acc;
        }
    }
}

extern "C" void kernel_launch(void* const* d_in, const int* in_sizes, int n_in,
                              void* d_out, int out_size, void* d_ws, size_t ws_size,
                              hipStream_t stream) {
    const float* c1   = (const float*)d_in[0];
    const float* c2   = (const float*)d_in[1];
    const float* outp = (const float*)d_in[2];
    const float* wr   = (const float*)d_in[3];
    const float* wr2  = (const float*)d_in[4];
    float* res = (float*)d_out;

    // ws: q 8.39MB | kfs 2.10MB | kft 8.39MB | wbuf 4.19MB  (total ~23.1MB)
    float* q_ws   = (float*)d_ws;
    float* kfs_ws = (float*)((char*)d_ws + 8388608);
    float* kft_ws = (float*)((char*)d_ws + 8388608 + 2097152);
    float* w_ws   = (float*)((char*)d_ws + 8388608 + 2097152 + 8388608);

    hipLaunchKernelGGL(k_q,      dim3(512),  dim3(512),  0, stream, c1, wr, q_ws);
    hipLaunchKernelGGL(k_kfs,    dim3(256),  dim3(1024), 0, stream, c2, wr2, kfs_ws);
    hipLaunchKernelGGL(k_upnorm, dim3(256),  dim3(256),  0, stream, kfs_ws, kft_ws);
    hipLaunchKernelGGL(k_att_w,  dim3(256),  dim3(256),  0, stream, q_ws, kft_ws, w_ws);
    hipLaunchKernelGGL(k_agg,    dim3(2048), dim3(256),  0, stream, w_ws, outp, res);
}

// Round 5
// 81.215 us; speedup vs baseline: 4.0218x; 1.0732x over previous
//
#include <hip/hip_runtime.h>
#include <hip/hip_bf16.h>

// Shapes: c1[4,256,128,128], c2[4,512,64,64], out[4,256,64,64],
//         w_refine[32,256], w_refine2[32,512]  -> result[4,256,128,128] (f32)

typedef float f32x4 __attribute__((ext_vector_type(4)));
typedef float f32x2 __attribute__((ext_vector_type(2)));

#define SCL (63.0f / 127.0f)

// ---------------- K1: qraw = c1 @ w_refine^T (UNNORMALIZED; normalize fused into k_att_w)
// 512 blocks x 512 thr = 8 waves: wave = (cg in 4 x og in 2). 2 pixels/lane.
__global__ __launch_bounds__(512) void k_q(const float* __restrict__ c1,
                                           const float* __restrict__ wr,
                                           float* __restrict__ q) {
    __shared__ float red[4 * 32 * 130];    // [cg][k(32)][130] transposed, 66.6 KB
    int b = blockIdx.x;                    // 128 blocks per n
    int n = b >> 7;
    int pblk = (b & 127) * 128;
    int t = threadIdx.x;
    int lane = t & 63;
    int w = t >> 6;
    int cg = __builtin_amdgcn_readfirstlane(w & 3);    // channel group: 64 ch
    int og = __builtin_amdgcn_readfirstlane(w >> 2);   // output group: 16 out

    const float* src = c1 + ((size_t)n * 256 + cg * 64) * 16384 + pblk + lane * 2;
    const float* wp  = wr + (og * 16) * 256 + cg * 64;

    float acc0[16], acc1[16];
#pragma unroll
    for (int o = 0; o < 16; ++o) { acc0[o] = 0.f; acc1[o] = 0.f; }
#pragma unroll 4
    for (int c = 0; c < 64; ++c) {
        f32x2 v = *(const f32x2*)(src + (size_t)c * 16384);   // coalesced 512B/wave
#pragma unroll
        for (int o = 0; o < 16; ++o) {
            float wv = wp[o * 256 + c];                        // wave-uniform s_load
            acc0[o] = fmaf(v[0], wv, acc0[o]);
            acc1[o] = fmaf(v[1], wv, acc1[o]);
        }
    }
#pragma unroll
    for (int o = 0; o < 16; ++o) {
        f32x2 pr = { acc0[o], acc1[o] };
        *(f32x2*)&red[(cg * 32 + og * 16 + o) * 130 + lane * 2] = pr;
    }
    __syncthreads();

    if (t < 256) {
        int px = t & 127, half = t >> 7;
        float v[16];
#pragma unroll
        for (int o = 0; o < 16; ++o) {
            v[o] = red[(0 * 32 + half * 16 + o) * 130 + px]
                 + red[(1 * 32 + half * 16 + o) * 130 + px]
                 + red[(2 * 32 + half * 16 + o) * 130 + px]
                 + red[(3 * 32 + half * 16 + o) * 130 + px];
        }
        float* dst = q + ((size_t)n * 16384 + pblk + px) * 32 + half * 16;
#pragma unroll
        for (int j = 0; j < 4; ++j) {
            f32x4 o4 = { v[4*j], v[4*j+1], v[4*j+2], v[4*j+3] };
            *(f32x4*)(dst + 4 * j) = o4;
        }
    }
}

// ---------------- K2: kfs = c2 @ w_refine2^T at 64x64 (UNNORMALIZED), [n*4096 pix][32]
// 256 blocks x 1024 thr = 16 waves: wave = (cg in 8 x og in 2). 1 pixel/lane.
__global__ __launch_bounds__(1024) void k_kfs(const float* __restrict__ c2,
                                              const float* __restrict__ wr2,
                                              float* __restrict__ kfs) {
    __shared__ float red[8 * 32 * 66];     // 67.6 KB
    int b = blockIdx.x;                    // 64 blocks per n
    int n = b >> 6;
    int pblk = (b & 63) * 64;
    int t = threadIdx.x;
    int lane = t & 63;
    int w = t >> 6;
    int cg = __builtin_amdgcn_readfirstlane(w & 7);    // 64 ch
    int og = __builtin_amdgcn_readfirstlane(w >> 3);   // 16 out

    const float* src = c2 + ((size_t)n * 512 + cg * 64) * 4096 + pblk + lane;
    const float* wp  = wr2 + (og * 16) * 512 + cg * 64;

    float acc[16];
#pragma unroll
    for (int o = 0; o < 16; ++o) acc[o] = 0.f;
#pragma unroll 4
    for (int c = 0; c < 64; ++c) {
        float v = src[(size_t)c * 4096];
#pragma unroll
        for (int o = 0; o < 16; ++o)
            acc[o] = fmaf(v, wp[o * 512 + c], acc[o]);
    }
#pragma unroll
    for (int o = 0; o < 16; ++o)
        red[(cg * 32 + og * 16 + o) * 66 + lane] = acc[o];
    __syncthreads();

    if (t < 512) {
        int px = t & 63, seg = t >> 6;
        float v[4];
#pragma unroll
        for (int j = 0; j < 4; ++j) {
            float r = 0.f;
#pragma unroll
            for (int g = 0; g < 8; ++g) r += red[(g * 32 + seg * 4 + j) * 66 + px];
            v[j] = r;
        }
        f32x4 o4 = { v[0], v[1], v[2], v[3] };
        *(f32x4*)(kfs + ((size_t)n * 4096 + pblk + px) * 32 + seg * 4) = o4;
    }
}

// ---------------- K3: kft = normalize_c( bilinear_up(kfs, 64->128) )
// 4 threads per pixel (quarter = 8 floats). 1024 blocks x 256 thr = 4096 waves.
__global__ __launch_bounds__(256) void k_upnorm(const float* __restrict__ kfs,
                                                float* __restrict__ kft) {
    int g = blockIdx.x * 256 + threadIdx.x;
    int p = g >> 2, qt = g & 3;
    int n = p >> 14;
    int rem = p & 16383;
    int y = rem >> 7, x = rem & 127;
    float syf = SCL * (float)y; int y0 = (int)syf; float fy = syf - (float)y0;
    int y1 = min(y0 + 1, 63);
    float sxf = SCL * (float)x; int x0 = (int)sxf; float fx = sxf - (float)x0;
    int x1 = min(x0 + 1, 63);
    size_t base = (size_t)n * 4096 * 32 + qt * 8;
    const f32x4* p00 = (const f32x4*)(kfs + base + ((size_t)(y0 * 64 + x0)) * 32);
    const f32x4* p01 = (const f32x4*)(kfs + base + ((size_t)(y0 * 64 + x1)) * 32);
    const f32x4* p10 = (const f32x4*)(kfs + base + ((size_t)(y1 * 64 + x0)) * 32);
    const f32x4* p11 = (const f32x4*)(kfs + base + ((size_t)(y1 * 64 + x1)) * 32);
    float w00 = (1.f-fy)*(1.f-fx), w01 = (1.f-fy)*fx, w10 = fy*(1.f-fx), w11 = fy*fx;
    float v[8]; float s = 0.f;
#pragma unroll
    for (int j = 0; j < 2; ++j) {
        f32x4 a = p00[j], b = p01[j], c = p10[j], d = p11[j];
#pragma unroll
        for (int tt = 0; tt < 4; ++tt) {
            float r = a[tt]*w00 + b[tt]*w01 + c[tt]*w10 + d[tt]*w11;
            v[4*j + tt] = r;
            s = fmaf(r, r, s);
        }
    }
    s += __shfl_xor(s, 1, 4);
    s += __shfl_xor(s, 2, 4);
    float inv = 1.0f / fmaxf(sqrtf(s), 1e-12f);
    f32x4* dst = (f32x4*)(kft + (size_t)p * 32 + qt * 8);
#pragma unroll
    for (int j = 0; j < 2; ++j) {
        f32x4 t = { v[4*j]*inv, v[4*j+1]*inv, v[4*j+2]*inv, v[4*j+3]*inv };
        dst[j] = t;
    }
}

// ---------------- K4a: normalize(q) -> energies -> softmax -> 16 combined weights
// 4 threads per pixel (8 channels each); 4-lane shuffle reduce; lane-replicated
// softmax+scatter (same-address LDS writes of identical values are broadcast-safe).
// wbuf layout TRANSPOSED: wbuf[i*65536 + p]. 1024 blocks x 256 thr.
__global__ __launch_bounds__(256) void k_att_w(const float* __restrict__ q,
                                               const float* __restrict__ kft,
                                               float* __restrict__ wbuf) {
    __shared__ float wsc[64 * 17];
    int t = threadIdx.x;
    int g = blockIdx.x * 256 + t;
    int p = g >> 2, qt = g & 3;
    int n = p >> 14, rem = p & 16383;
    int y = rem >> 7, x = rem & 127;
    int pixL = t >> 2;

    int ybase = min((int)(SCL * (float)max(y - 2, 0)), 60);
    int xbase = min((int)(SCL * (float)max(x - 2, 0)), 60);

    // quarter of raw q (8 floats, 32B coalesced)
    const f32x4* qp = (const f32x4*)(q + (size_t)p * 32 + qt * 8);
    f32x4 q0 = qp[0], q1 = qp[1];
    float qs = 0.f;
#pragma unroll
    for (int tt = 0; tt < 4; ++tt) { qs = fmaf(q0[tt], q0[tt], qs); qs = fmaf(q1[tt], q1[tt], qs); }

    // partial energies over this lane's 8 channels
    float d[9];
#pragma unroll
    for (int k = 0; k < 9; ++k) {
        int ky = k / 3, kx = k % 3;
        int ny = y + 2 * ky - 2, nx = x + 2 * kx - 2;
        float acc = 0.f;
        if (ny >= 0 && ny < 128 && nx >= 0 && nx < 128) {
            const f32x4* kp = (const f32x4*)(kft + ((size_t)n * 16384 + ny * 128 + nx) * 32 + qt * 8);
            f32x4 a = kp[0], b = kp[1];
            acc = fmaf(a[0], q0[0], acc); acc = fmaf(a[1], q0[1], acc);
            acc = fmaf(a[2], q0[2], acc); acc = fmaf(a[3], q0[3], acc);
            acc = fmaf(b[0], q1[0], acc); acc = fmaf(b[1], q1[1], acc);
            acc = fmaf(b[2], q1[2], acc); acc = fmaf(b[3], q1[3], acc);
        }
        d[k] = acc;
    }
    // 4-lane butterfly reduce (10 scalars)
    qs += __shfl_xor(qs, 1, 4); qs += __shfl_xor(qs, 2, 4);
#pragma unroll
    for (int k = 0; k < 9; ++k) {
        d[k] += __shfl_xor(d[k], 1, 4);
        d[k] += __shfl_xor(d[k], 2, 4);
    }
    float qinv = 1.0f / fmaxf(sqrtf(qs), 1e-12f);

    float e[9];
    float m = d[0] * qinv;
#pragma unroll
    for (int k = 0; k < 9; ++k) { e[k] = d[k] * qinv; if (k) m = fmaxf(m, e[k]); }
    float ssum = 0.f;
#pragma unroll
    for (int k = 0; k < 9; ++k) { e[k] = __expf(e[k] - m); ssum += e[k]; }
    float rinv = 1.0f / ssum;

    // scatter att*bilinear into 16 slots (replicated on the 4 lanes; identical values)
    float* wp = wsc + pixL * 17;
#pragma unroll
    for (int i = 0; i < 16; ++i) wp[i] = 0.f;
#pragma unroll
    for (int ky = 0; ky < 3; ++ky) {
        int ny = y + 2 * ky - 2;
        if (ny < 0 || ny > 127) continue;
        float syf = SCL * (float)ny; int iy0 = (int)syf; float fy = syf - (float)iy0;
        int iy1 = min(iy0 + 1, 63);
        int r0 = (iy0 - ybase) * 4, r1 = (iy1 - ybase) * 4;
#pragma unroll
        for (int kx = 0; kx < 3; ++kx) {
            int nx = x + 2 * kx - 2;
            if (nx < 0 || nx > 127) continue;
            float sxf = SCL * (float)nx; int ix0 = (int)sxf; float fx = sxf - (float)ix0;
            int ix1 = min(ix0 + 1, 63);
            float a = e[ky * 3 + kx] * rinv;
            wp[r0 + (ix0 - xbase)] += a * (1.f - fy) * (1.f - fx);
            wp[r0 + (ix1 - xbase)] += a * (1.f - fy) * fx;
            wp[r1 + (ix0 - xbase)] += a * fy * (1.f - fx);
            wp[r1 + (ix1 - xbase)] += a * fy * fx;
        }
    }
    __syncthreads();

    // transposed coalesced store: 64 px x 16 i, 4 per thread
    int px = t & 63, i0 = t >> 6;
    int pb = blockIdx.x * 64;
#pragma unroll
    for (int r = 0; r < 4; ++r) {
        int i = r * 4 + i0;
        wbuf[i * 65536 + pb + px] = wsc[px * 17 + i];
    }
}

// ---------------- K4b: aggregate out planes with combined weights (LDS-staged, dense loads)
// grid 2048 = n(4) x y(128) x cg(4); 256 thr: x = t&127, half = t>>7 (4 channels each)
__global__ __launch_bounds__(256) void k_agg(const float* __restrict__ wbuf,
                                             const float* __restrict__ outp,
                                             float* __restrict__ res) {
    __shared__ float wlds[128 * 17];
    __shared__ float tile[8 * 260];
    int b = blockIdx.x;
    int cg = b & 3, y = (b >> 2) & 127, n = b >> 9;
    int t = threadIdx.x;
    int x = t & 127, half = t >> 7;

    int ybase = min((int)(SCL * (float)max(y - 2, 0)), 60);
    int pix = n * 16384 + y * 128;

#pragma unroll
    for (int k = 0; k < 8; ++k) {
        int u = t + 256 * k;
        int i = u >> 7, xx = u & 127;
        wlds[xx * 17 + i] = wbuf[i * 65536 + pix + xx];
    }
    __syncthreads();
    float w16[16];
#pragma unroll
    for (int i = 0; i < 16; ++i) w16[i] = wlds[x * 17 + i];
    int xb = min((int)(SCL * (float)max(x - 2, 0)), 60);

    const float* ob = outp + ((size_t)n * 256 + cg * 64) * 4096 + ybase * 64;
    float* rb = res + ((size_t)n * 256 + cg * 64) * 16384 + y * 128 + x;

#pragma unroll 1
    for (int batch = 0; batch < 8; ++batch) {
        __syncthreads();
        const float* src = ob + (size_t)batch * 8 * 4096;
#pragma unroll
        for (int k = 0; k < 2; ++k) {
            int u = t + 256 * k;
            int cl = u >> 6, seg = u & 63;
            f32x4 v = *(const f32x4*)(src + (size_t)cl * 4096 + seg * 4);
            *(f32x4*)&tile[cl * 260 + seg * 4] = v;
        }
        __syncthreads();
#pragma unroll
        for (int cl = 0; cl < 4; ++cl) {
            int c = half * 4 + cl;
            const float* tp = tile + c * 260 + xb;
            float acc = 0.f;
#pragma unroll
            for (int r = 0; r < 4; ++r) {
                acc = fmaf(tp[r*64 + 0], w16[r*4 + 0], acc);
                acc = fmaf(tp[r*64 + 1], w16[r*4 + 1], acc);
                acc = fmaf(tp[r*64 + 2], w16[r*4 + 2], acc);
                acc = fmaf(tp[r*64 + 3], w16[r*4 + 3], acc);
            }
            rb[(size_t)(batch * 8 + c) * 16384] = acc;
        }
    }
}

extern "C" void kernel_launch(void* const* d_in, const int* in_sizes, int n_in,
                              void* d_out, int out_size, void* d_ws, size_t ws_size,
                              hipStream_t stream) {
    const float* c1   = (const float*)d_in[0];
    const float* c2   = (const float*)d_in[1];
    const float* outp = (const float*)d_in[2];
    const float* wr   = (const float*)d_in[3];
    const float* wr2  = (const float*)d_in[4];
    float* res = (float*)d_out;

    // ws: q 8.39MB | kfs 2.10MB | kft 8.39MB | wbuf 4.19MB  (total ~23.1MB)
    float* q_ws   = (float*)d_ws;
    float* kfs_ws = (float*)((char*)d_ws + 8388608);
    float* kft_ws = (float*)((char*)d_ws + 8388608 + 2097152);
    float* w_ws   = (float*)((char*)d_ws + 8388608 + 2097152 + 8388608);

    hipLaunchKernelGGL(k_q,      dim3(512),  dim3(512),  0, stream, c1, wr, q_ws);
    hipLaunchKernelGGL(k_kfs,    dim3(256),  dim3(1024), 0, stream, c2, wr2, kfs_ws);
    hipLaunchKernelGGL(k_upnorm, dim3(1024), dim3(256),  0, stream, kfs_ws, kft_ws);
    hipLaunchKernelGGL(k_att_w,  dim3(1024), dim3(256),  0, stream, q_ws, kft_ws, w_ws);
    hipLaunchKernelGGL(k_agg,    dim3(2048), dim3(256),  0, stream, w_ws, outp, res);
}

// Round 6
// 74.899 us; speedup vs baseline: 4.3610x; 1.0843x over previous
//
#include <hip/hip_runtime.h>
#include <hip/hip_bf16.h>

// Shapes: c1[4,256,128,128], c2[4,512,64,64], out[4,256,64,64],
//         w_refine[32,256], w_refine2[32,512]  -> result[4,256,128,128] (f32)

typedef float f32x4 __attribute__((ext_vector_type(4)));
typedef float f32x2 __attribute__((ext_vector_type(2)));

#define SCL (63.0f / 127.0f)

// ---------------- K2: kfs = c2 @ w_refine2^T at 64x64 (UNNORMALIZED), [n*4096 pix][32]
// 256 blocks x 1024 thr = 16 waves: wave = (cg in 8 x og in 2). 1 pixel/lane.
__global__ __launch_bounds__(1024) void k_kfs(const float* __restrict__ c2,
                                              const float* __restrict__ wr2,
                                              float* __restrict__ kfs) {
    __shared__ float red[8 * 32 * 66];     // 67.6 KB
    int b = blockIdx.x;                    // 64 blocks per n
    int n = b >> 6;
    int pblk = (b & 63) * 64;
    int t = threadIdx.x;
    int lane = t & 63;
    int w = t >> 6;
    int cg = __builtin_amdgcn_readfirstlane(w & 7);    // 64 ch
    int og = __builtin_amdgcn_readfirstlane(w >> 3);   // 16 out

    const float* src = c2 + ((size_t)n * 512 + cg * 64) * 4096 + pblk + lane;
    const float* wp  = wr2 + (og * 16) * 512 + cg * 64;

    float acc[16];
#pragma unroll
    for (int o = 0; o < 16; ++o) acc[o] = 0.f;
#pragma unroll 4
    for (int c = 0; c < 64; ++c) {
        float v = src[(size_t)c * 4096];
#pragma unroll
        for (int o = 0; o < 16; ++o)
            acc[o] = fmaf(v, wp[o * 512 + c], acc[o]);
    }
#pragma unroll
    for (int o = 0; o < 16; ++o)
        red[(cg * 32 + og * 16 + o) * 66 + lane] = acc[o];
    __syncthreads();

    if (t < 512) {
        int px = t & 63, seg = t >> 6;
        float v[4];
#pragma unroll
        for (int j = 0; j < 4; ++j) {
            float r = 0.f;
#pragma unroll
            for (int g = 0; g < 8; ++g) r += red[(g * 32 + seg * 4 + j) * 66 + px];
            v[j] = r;
        }
        f32x4 o4 = { v[0], v[1], v[2], v[3] };
        *(f32x4*)(kfs + ((size_t)n * 4096 + pblk + px) * 32 + seg * 4) = o4;
    }
}

// ---------------- K3: kft = normalize_c( bilinear_up(kfs, 64->128) )
// 4 threads per pixel (quarter = 8 floats). 1024 blocks x 256 thr.
__global__ __launch_bounds__(256) void k_upnorm(const float* __restrict__ kfs,
                                                float* __restrict__ kft) {
    int g = blockIdx.x * 256 + threadIdx.x;
    int p = g >> 2, qt = g & 3;
    int n = p >> 14;
    int rem = p & 16383;
    int y = rem >> 7, x = rem & 127;
    float syf = SCL * (float)y; int y0 = (int)syf; float fy = syf - (float)y0;
    int y1 = min(y0 + 1, 63);
    float sxf = SCL * (float)x; int x0 = (int)sxf; float fx = sxf - (float)x0;
    int x1 = min(x0 + 1, 63);
    size_t base = (size_t)n * 4096 * 32 + qt * 8;
    const f32x4* p00 = (const f32x4*)(kfs + base + ((size_t)(y0 * 64 + x0)) * 32);
    const f32x4* p01 = (const f32x4*)(kfs + base + ((size_t)(y0 * 64 + x1)) * 32);
    const f32x4* p10 = (const f32x4*)(kfs + base + ((size_t)(y1 * 64 + x0)) * 32);
    const f32x4* p11 = (const f32x4*)(kfs + base + ((size_t)(y1 * 64 + x1)) * 32);
    float w00 = (1.f-fy)*(1.f-fx), w01 = (1.f-fy)*fx, w10 = fy*(1.f-fx), w11 = fy*fx;
    float v[8]; float s = 0.f;
#pragma unroll
    for (int j = 0; j < 2; ++j) {
        f32x4 a = p00[j], b = p01[j], c = p10[j], d = p11[j];
#pragma unroll
        for (int tt = 0; tt < 4; ++tt) {
            float r = a[tt]*w00 + b[tt]*w01 + c[tt]*w10 + d[tt]*w11;
            v[4*j + tt] = r;
            s = fmaf(r, r, s);
        }
    }
    s += __shfl_xor(s, 1, 4);
    s += __shfl_xor(s, 2, 4);
    float inv = 1.0f / fmaxf(sqrtf(s), 1e-12f);
    f32x4* dst = (f32x4*)(kft + (size_t)p * 32 + qt * 8);
#pragma unroll
    for (int j = 0; j < 2; ++j) {
        f32x4 t = { v[4*j]*inv, v[4*j+1]*inv, v[4*j+2]*inv, v[4*j+3]*inv };
        dst[j] = t;
    }
}

// ---------------- K_FQ (fused): qraw GEMM (in LDS) -> normalize -> energies vs kft
// -> softmax -> 16 combined weights -> wbuf.  512 blocks x 512 thr; block = row y of image n.
// LDS: one 66.56KB buffer; phase1 uses it as red[4cg][32k][130]; after barrier it is
// reused as qlds[128][33] (offset 0) + wsc[128][17] (offset 8192 floats).
__global__ __launch_bounds__(512) void k_fq(const float* __restrict__ c1,
                                            const float* __restrict__ wr,
                                            const float* __restrict__ kft,
                                            float* __restrict__ wbuf) {
    __shared__ float smem[16640];
    int b = blockIdx.x;                    // 128 blocks per n
    int n = b >> 7;
    int y = b & 127;
    int pblk = y * 128;
    int t = threadIdx.x;
    int lane = t & 63;
    int w = t >> 6;
    int cg = __builtin_amdgcn_readfirstlane(w & 3);    // channel group: 64 ch
    int og = __builtin_amdgcn_readfirstlane(w >> 2);   // output group: 16 out

    // ---- phase 1: raw q GEMM (identical structure to old k_q)
    {
        const float* src = c1 + ((size_t)n * 256 + cg * 64) * 16384 + pblk + lane * 2;
        const float* wp  = wr + (og * 16) * 256 + cg * 64;
        float acc0[16], acc1[16];
#pragma unroll
        for (int o = 0; o < 16; ++o) { acc0[o] = 0.f; acc1[o] = 0.f; }
#pragma unroll 4
        for (int c = 0; c < 64; ++c) {
            f32x2 v = *(const f32x2*)(src + (size_t)c * 16384);   // coalesced 512B/wave
#pragma unroll
            for (int o = 0; o < 16; ++o) {
                float wv = wp[o * 256 + c];                        // wave-uniform s_load
                acc0[o] = fmaf(v[0], wv, acc0[o]);
                acc1[o] = fmaf(v[1], wv, acc1[o]);
            }
        }
#pragma unroll
        for (int o = 0; o < 16; ++o) {
            f32x2 pr = { acc0[o], acc1[o] };
            *(f32x2*)&smem[(cg * 32 + og * 16 + o) * 130 + lane * 2] = pr;
        }
    }
    __syncthreads();

    // ---- reduce 4 cg partials; park in registers, then overlay qlds[128][33]
    float v16[16];
    {
        int px = t & 127, half = (t >> 7) & 1;
        if (t < 256) {
#pragma unroll
            for (int o = 0; o < 16; ++o) {
                v16[o] = smem[(0 * 32 + half * 16 + o) * 130 + px]
                       + smem[(1 * 32 + half * 16 + o) * 130 + px]
                       + smem[(2 * 32 + half * 16 + o) * 130 + px]
                       + smem[(3 * 32 + half * 16 + o) * 130 + px];
            }
        }
    }
    __syncthreads();   // all reads of red done before overwrite
    if (t < 256) {
        int px = t & 127, half = (t >> 7) & 1;
#pragma unroll
        for (int o = 0; o < 16; ++o) smem[px * 33 + half * 16 + o] = v16[o];
    }
    __syncthreads();

    // ---- phase 2: 4 threads per pixel (8 channels each)
    int px = t >> 2, qt = t & 3;           // px = x in [0,128)
    int x = px;
    int ybase = min((int)(SCL * (float)max(y - 2, 0)), 60);   // block-uniform
    int xbase = min((int)(SCL * (float)max(x - 2, 0)), 60);

    float qv[8];
#pragma unroll
    for (int j = 0; j < 8; ++j) qv[j] = smem[px * 33 + qt * 8 + j];
    float qs = 0.f;
#pragma unroll
    for (int j = 0; j < 8; ++j) qs = fmaf(qv[j], qv[j], qs);

    float d[9];
#pragma unroll
    for (int ky = 0; ky < 3; ++ky) {
        int ny = y + 2 * ky - 2;                      // uniform
        bool rowOK = (ny >= 0) && (ny < 128);
#pragma unroll
        for (int kx = 0; kx < 3; ++kx) {
            int nx = x + 2 * kx - 2;
            float acc = 0.f;
            if (rowOK && nx >= 0 && nx < 128) {
                const f32x4* kp = (const f32x4*)(kft + ((size_t)n * 16384 + ny * 128 + nx) * 32 + qt * 8);
                f32x4 a = kp[0], b2 = kp[1];
                acc = fmaf(a[0],  qv[0], acc); acc = fmaf(a[1],  qv[1], acc);
                acc = fmaf(a[2],  qv[2], acc); acc = fmaf(a[3],  qv[3], acc);
                acc = fmaf(b2[0], qv[4], acc); acc = fmaf(b2[1], qv[5], acc);
                acc = fmaf(b2[2], qv[6], acc); acc = fmaf(b2[3], qv[7], acc);
            }
            d[ky * 3 + kx] = acc;
        }
    }
    qs += __shfl_xor(qs, 1, 4); qs += __shfl_xor(qs, 2, 4);
#pragma unroll
    for (int k = 0; k < 9; ++k) {
        d[k] += __shfl_xor(d[k], 1, 4);
        d[k] += __shfl_xor(d[k], 2, 4);
    }
    float qinv = 1.0f / fmaxf(sqrtf(qs), 1e-12f);

    float e[9];
    float m = d[0] * qinv;
#pragma unroll
    for (int k = 0; k < 9; ++k) { e[k] = d[k] * qinv; if (k) m = fmaxf(m, e[k]); }
    float ssum = 0.f;
#pragma unroll
    for (int k = 0; k < 9; ++k) { e[k] = __expf(e[k] - m); ssum += e[k]; }
    float rinv = 1.0f / ssum;

    // scatter att*bilinear into 16 slots (4 replica lanes, lockstep same-address = safe)
    float* wp = smem + 8192 + px * 17;
#pragma unroll
    for (int i = 0; i < 16; ++i) wp[i] = 0.f;
#pragma unroll
    for (int ky = 0; ky < 3; ++ky) {
        int ny = y + 2 * ky - 2;
        if (ny < 0 || ny > 127) continue;
        float syf = SCL * (float)ny; int iy0 = (int)syf; float fy = syf - (float)iy0;
        int iy1 = min(iy0 + 1, 63);
        int r0 = (iy0 - ybase) * 4, r1 = (iy1 - ybase) * 4;
#pragma unroll
        for (int kx = 0; kx < 3; ++kx) {
            int nx = x + 2 * kx - 2;
            if (nx < 0 || nx > 127) continue;
            float sxf = SCL * (float)nx; int ix0 = (int)sxf; float fx = sxf - (float)ix0;
            int ix1 = min(ix0 + 1, 63);
            float a = e[ky * 3 + kx] * rinv;
            wp[r0 + (ix0 - xbase)] += a * (1.f - fy) * (1.f - fx);
            wp[r0 + (ix1 - xbase)] += a * (1.f - fy) * fx;
            wp[r1 + (ix0 - xbase)] += a * fy * (1.f - fx);
            wp[r1 + (ix1 - xbase)] += a * fy * fx;
        }
    }
    __syncthreads();

    // transposed coalesced store: 128 px x 16 i, 4 per thread
    int sx = t & 127, i0 = t >> 7;
    int pg = n * 16384 + y * 128 + sx;
#pragma unroll
    for (int r = 0; r < 4; ++r) {
        int i = r * 4 + i0;
        wbuf[i * 65536 + pg] = smem[8192 + sx * 17 + i];
    }
}

// ---------------- K4b: aggregate out planes with combined weights (LDS-staged, dense loads)
// grid 2048 = n(4) x y(128) x cg(4); 256 thr: x = t&127, half = t>>7 (4 channels each)
__global__ __launch_bounds__(256) void k_agg(const float* __restrict__ wbuf,
                                             const float* __restrict__ outp,
                                             float* __restrict__ res) {
    __shared__ float wlds[128 * 17];
    __shared__ float tile[8 * 260];
    int b = blockIdx.x;
    int cg = b & 3, y = (b >> 2) & 127, n = b >> 9;
    int t = threadIdx.x;
    int x = t & 127, half = t >> 7;

    int ybase = min((int)(SCL * (float)max(y - 2, 0)), 60);
    int pix = n * 16384 + y * 128;

#pragma unroll
    for (int k = 0; k < 8; ++k) {
        int u = t + 256 * k;
        int i = u >> 7, xx = u & 127;
        wlds[xx * 17 + i] = wbuf[i * 65536 + pix + xx];
    }
    __syncthreads();
    float w16[16];
#pragma unroll
    for (int i = 0; i < 16; ++i) w16[i] = wlds[x * 17 + i];
    int xb = min((int)(SCL * (float)max(x - 2, 0)), 60);

    const float* ob = outp + ((size_t)n * 256 + cg * 64) * 4096 + ybase * 64;
    float* rb = res + ((size_t)n * 256 + cg * 64) * 16384 + y * 128 + x;

#pragma unroll 1
    for (int batch = 0; batch < 8; ++batch) {
        __syncthreads();
        const float* src = ob + (size_t)batch * 8 * 4096;
#pragma unroll
        for (int k = 0; k < 2; ++k) {
            int u = t + 256 * k;
            int cl = u >> 6, seg = u & 63;
            f32x4 v = *(const f32x4*)(src + (size_t)cl * 4096 + seg * 4);
            *(f32x4*)&tile[cl * 260 + seg * 4] = v;
        }
        __syncthreads();
#pragma unroll
        for (int cl = 0; cl < 4; ++cl) {
            int c = half * 4 + cl;
            const float* tp = tile + c * 260 + xb;
            float acc = 0.f;
#pragma unroll
            for (int r = 0; r < 4; ++r) {
                acc = fmaf(tp[r*64 + 0], w16[r*4 + 0], acc);
                acc = fmaf(tp[r*64 + 1], w16[r*4 + 1], acc);
                acc = fmaf(tp[r*64 + 2], w16[r*4 + 2], acc);
                acc = fmaf(tp[r*64 + 3], w16[r*4 + 3], acc);
            }
            rb[(size_t)(batch * 8 + c) * 16384] = acc;
        }
    }
}

extern "C" void kernel_launch(void* const* d_in, const int* in_sizes, int n_in,
                              void* d_out, int out_size, void* d_ws, size_t ws_size,
                              hipStream_t stream) {
    const float* c1   = (const float*)d_in[0];
    const float* c2   = (const float*)d_in[1];
    const float* outp = (const float*)d_in[2];
    const float* wr   = (const float*)d_in[3];
    const float* wr2  = (const float*)d_in[4];
    float* res = (float*)d_out;

    // ws: kfs 2.10MB | kft 8.39MB | wbuf 4.19MB  (total ~14.7MB)
    float* kfs_ws = (float*)d_ws;
    float* kft_ws = (float*)((char*)d_ws + 2097152);
    float* w_ws   = (float*)((char*)d_ws + 2097152 + 8388608);

    hipLaunchKernelGGL(k_kfs,    dim3(256),  dim3(1024), 0, stream, c2, wr2, kfs_ws);
    hipLaunchKernelGGL(k_upnorm, dim3(1024), dim3(256),  0, stream, kfs_ws, kft_ws);
    hipLaunchKernelGGL(k_fq,     dim3(512),  dim3(512),  0, stream, c1, wr, kft_ws, w_ws);
    hipLaunchKernelGGL(k_agg,    dim3(2048), dim3(256),  0, stream, w_ws, outp, res);
}